// Round 2
// baseline (513.882 us; speedup 1.0000x reference)
//
#include <hip/hip_runtime.h>
#include <hip/hip_bf16.h>

// Problem constants (match reference setup_inputs)
#define N_NODES 50000
#define N_EDGES 800000
#define IN_DIM  128
#define HID     256
#define HID2    128   // HID/2

// ---------------------------------------------------------------------------
// CSR build.  NOTE: harness pushes integer inputs as int32 (see contract),
// so edge_index is const int* with layout [src[0..E), dst[0..E)].
// ---------------------------------------------------------------------------
__global__ void count_deg(const int* __restrict__ ei, int* __restrict__ cnt) {
    int e = blockIdx.x * blockDim.x + threadIdx.x;
    if (e < N_EDGES) atomicAdd(&cnt[ei[N_EDGES + e]], 1);
}

__global__ void calc_dis(const int* __restrict__ cnt, float* __restrict__ dis) {
    int i = blockIdx.x * blockDim.x + threadIdx.x;
    if (i < N_NODES) dis[i] = rsqrtf((float)(cnt[i] + 1));  // +1 self-loop
}

// single-block scan over N_NODES counts -> exclusive prefix (row_start)
__global__ void scan_counts(const int* __restrict__ cnt, int* __restrict__ row_start) {
    __shared__ int buf[1024];
    __shared__ int carry_s;
    int tid = threadIdx.x;
    if (tid == 0) carry_s = 0;
    __syncthreads();
    for (int base = 0; base < N_NODES; base += 1024) {
        int i = base + tid;
        int v = (i < N_NODES) ? cnt[i] : 0;
        buf[tid] = v;
        __syncthreads();
        int acc = v;
        for (int off = 1; off < 1024; off <<= 1) {
            int t = (tid >= off) ? buf[tid - off] : 0;
            __syncthreads();
            acc += t;
            buf[tid] = acc;
            __syncthreads();
        }
        int carry = carry_s;
        if (i < N_NODES) row_start[i] = carry + acc - v;   // exclusive
        __syncthreads();
        if (tid == 1023) carry_s = carry + acc;            // acc == chunk total
        __syncthreads();
    }
    if (tid == 0) row_start[N_NODES] = carry_s;
}

__global__ void fill_csr(const int* __restrict__ ei,
                         const int* __restrict__ row_start,
                         int* __restrict__ cursor,
                         const float* __restrict__ dis,
                         int* __restrict__ srcs, float* __restrict__ wn) {
    int e = blockIdx.x * blockDim.x + threadIdx.x;
    if (e < N_EDGES) {
        int s = ei[e];
        int d = ei[N_EDGES + e];
        int slot = row_start[d] + atomicAdd(&cursor[d], 1);
        srcs[slot] = s;
        wn[slot] = dis[s] * dis[d];
    }
}

// ---------------------------------------------------------------------------
// Aggregation 1: out[i,:] = dis[i]^2 * X[i,:] + sum_e wn[e] * X[src[e],:]
// block = 128 threads (one column each), grid = N_NODES
// ---------------------------------------------------------------------------
__global__ __launch_bounds__(128)
void agg_x(const float* __restrict__ X, const float* __restrict__ dis,
           const int* __restrict__ row_start, const int* __restrict__ srcs,
           const float* __restrict__ wn, float* __restrict__ out) {
    int i = blockIdx.x;
    int c = threadIdx.x;
    float di = dis[i];
    float acc = di * di * X[(size_t)i * IN_DIM + c];
    int e0 = row_start[i], e1 = row_start[i + 1];
    for (int e = e0; e < e1; ++e) {
        int s = srcs[e];
        float w = wn[e];
        acc += w * X[(size_t)s * IN_DIM + c];
    }
    out[(size_t)i * IN_DIM + c] = acc;
}

// ---------------------------------------------------------------------------
// Aggregation 2 fused with bias+ReLU+dot(Wfc)+global reduce.
// grid-stride over nodes; one block-level atomicAdd at the end.
// ---------------------------------------------------------------------------
__global__ __launch_bounds__(128)
void agg_g_pool(const float* __restrict__ G, const float* __restrict__ dis,
                const int* __restrict__ row_start, const int* __restrict__ srcs,
                const float* __restrict__ wn, const float* __restrict__ b2,
                const float* __restrict__ wfc, float* __restrict__ accbuf) {
    int c = threadIdx.x;
    float bc = b2[c];
    float wc = wfc[c];
    float part = 0.f;
    for (int i = blockIdx.x; i < N_NODES; i += gridDim.x) {
        float di = dis[i];
        float acc = di * di * G[(size_t)i * HID2 + c];
        int e0 = row_start[i], e1 = row_start[i + 1];
        for (int e = e0; e < e1; ++e) {
            acc += wn[e] * G[(size_t)srcs[e] * HID2 + c];
        }
        part += fmaxf(acc + bc, 0.f) * wc;
    }
    __shared__ float red[128];
    red[c] = part;
    __syncthreads();
    for (int off = 64; off > 0; off >>= 1) {
        if (c < off) red[c] += red[c + off];
        __syncthreads();
    }
    if (c == 0) atomicAdd(accbuf, red[0]);
}

__global__ void finalize(const float* __restrict__ accbuf,
                         const float* __restrict__ bfc, float* __restrict__ out) {
    out[0] = accbuf[0] * (1.0f / (float)N_NODES) + bfc[0];
}

// ---------------------------------------------------------------------------
// fp32 GEMM: C[M,N] = A[M,K] @ B[K,N]  (+bias, relu if RELU_BIAS)
// BM=64, BN=128, BK=32, 256 threads, 4x8 micro-tile per thread
// ---------------------------------------------------------------------------
template<bool RELU_BIAS>
__global__ __launch_bounds__(256)
void gemm64x128(const float* __restrict__ A, const float* __restrict__ B,
                const float* __restrict__ bias, float* __restrict__ C,
                int M, int N, int K) {
    __shared__ float As[64][33];    // [m][k], pad 33 -> conflict-free column reads
    __shared__ float Bs[32][128];   // [k][n]

    int tid = threadIdx.x;
    int row0 = blockIdx.x * 64;
    int col0 = blockIdx.y * 128;
    int ty = tid >> 4;   // 0..15 -> rows ty*4..+3
    int tx = tid & 15;   // cols tx*4 and 64+tx*4

    float acc[4][8];
#pragma unroll
    for (int i = 0; i < 4; ++i)
#pragma unroll
        for (int j = 0; j < 8; ++j) acc[i][j] = 0.f;

    int arow = tid >> 3;          // 0..31
    int akc  = (tid & 7) * 4;     // k offset (float4)
    int brow = tid >> 5;          // 0..7
    int bcol = (tid & 31) * 4;    // n offset (float4)

    for (int k0 = 0; k0 < K; k0 += 32) {
        // stage A tile (guarded rows)
#pragma unroll
        for (int r = 0; r < 2; ++r) {
            int m = arow + r * 32;
            int grow = row0 + m;
            float4 v = make_float4(0.f, 0.f, 0.f, 0.f);
            if (grow < M) v = *(const float4*)&A[(size_t)grow * K + k0 + akc];
            As[m][akc + 0] = v.x; As[m][akc + 1] = v.y;
            As[m][akc + 2] = v.z; As[m][akc + 3] = v.w;
        }
        // stage B tile
#pragma unroll
        for (int r = 0; r < 4; ++r) {
            int kr = brow + r * 8;
            *(float4*)&Bs[kr][bcol] = *(const float4*)&B[(size_t)(k0 + kr) * N + col0 + bcol];
        }
        __syncthreads();

#pragma unroll
        for (int kk = 0; kk < 32; ++kk) {
            float a0 = As[ty * 4 + 0][kk];
            float a1 = As[ty * 4 + 1][kk];
            float a2 = As[ty * 4 + 2][kk];
            float a3 = As[ty * 4 + 3][kk];
            float4 bl = *(const float4*)&Bs[kk][tx * 4];
            float4 bh = *(const float4*)&Bs[kk][64 + tx * 4];
            acc[0][0] += a0 * bl.x; acc[0][1] += a0 * bl.y; acc[0][2] += a0 * bl.z; acc[0][3] += a0 * bl.w;
            acc[0][4] += a0 * bh.x; acc[0][5] += a0 * bh.y; acc[0][6] += a0 * bh.z; acc[0][7] += a0 * bh.w;
            acc[1][0] += a1 * bl.x; acc[1][1] += a1 * bl.y; acc[1][2] += a1 * bl.z; acc[1][3] += a1 * bl.w;
            acc[1][4] += a1 * bh.x; acc[1][5] += a1 * bh.y; acc[1][6] += a1 * bh.z; acc[1][7] += a1 * bh.w;
            acc[2][0] += a2 * bl.x; acc[2][1] += a2 * bl.y; acc[2][2] += a2 * bl.z; acc[2][3] += a2 * bl.w;
            acc[2][4] += a2 * bh.x; acc[2][5] += a2 * bh.y; acc[2][6] += a2 * bh.z; acc[2][7] += a2 * bh.w;
            acc[3][0] += a3 * bl.x; acc[3][1] += a3 * bl.y; acc[3][2] += a3 * bl.z; acc[3][3] += a3 * bl.w;
            acc[3][4] += a3 * bh.x; acc[3][5] += a3 * bh.y; acc[3][6] += a3 * bh.z; acc[3][7] += a3 * bh.w;
        }
        __syncthreads();
    }

    // epilogue
    float blo[4], bhi[4];
    if (RELU_BIAS) {
#pragma unroll
        for (int j = 0; j < 4; ++j) {
            blo[j] = bias[col0 + tx * 4 + j];
            bhi[j] = bias[col0 + 64 + tx * 4 + j];
        }
    }
#pragma unroll
    for (int i = 0; i < 4; ++i) {
        int grow = row0 + ty * 4 + i;
        if (grow < M) {
            float4 lo = make_float4(acc[i][0], acc[i][1], acc[i][2], acc[i][3]);
            float4 hi = make_float4(acc[i][4], acc[i][5], acc[i][6], acc[i][7]);
            if (RELU_BIAS) {
                lo.x = fmaxf(lo.x + blo[0], 0.f); lo.y = fmaxf(lo.y + blo[1], 0.f);
                lo.z = fmaxf(lo.z + blo[2], 0.f); lo.w = fmaxf(lo.w + blo[3], 0.f);
                hi.x = fmaxf(hi.x + bhi[0], 0.f); hi.y = fmaxf(hi.y + bhi[1], 0.f);
                hi.z = fmaxf(hi.z + bhi[2], 0.f); hi.w = fmaxf(hi.w + bhi[3], 0.f);
            }
            *(float4*)&C[(size_t)grow * N + col0 + tx * 4] = lo;
            *(float4*)&C[(size_t)grow * N + col0 + 64 + tx * 4] = hi;
        }
    }
}

// ---------------------------------------------------------------------------
// launcher
// ---------------------------------------------------------------------------
extern "C" void kernel_launch(void* const* d_in, const int* in_sizes, int n_in,
                              void* d_out, int out_size, void* d_ws, size_t ws_size,
                              hipStream_t stream) {
    const float* x   = (const float*)d_in[0];
    const int*   ei  = (const int*)d_in[1];     // int32 per harness contract
    const float* W1  = (const float*)d_in[2];
    const float* b1  = (const float*)d_in[3];
    const float* W2  = (const float*)d_in[4];
    const float* b2  = (const float*)d_in[5];
    const float* Wfc = (const float*)d_in[6];
    const float* bfc = (const float*)d_in[7];
    float* out = (float*)d_out;

    // workspace carve-up (all offsets 256B aligned)
    char* ws = (char*)d_ws;
    size_t off = 0;
    auto carve = [&](size_t bytes) {
        void* p = ws + off;
        off += (bytes + 255) & ~(size_t)255;
        return p;
    };
    int*   cnt       = (int*)  carve((size_t)N_NODES * 4);
    int*   row_start = (int*)  carve((size_t)(N_NODES + 1) * 4);
    int*   cursor    = (int*)  carve((size_t)N_NODES * 4);
    float* dis       = (float*)carve((size_t)N_NODES * 4);
    int*   srcs      = (int*)  carve((size_t)N_EDGES * 4);
    float* wn        = (float*)carve((size_t)N_EDGES * 4);
    float* bufA      = (float*)carve((size_t)N_NODES * IN_DIM * 4);   // aggX, then G
    float* bufB      = (float*)carve((size_t)N_NODES * HID * 4);      // h1
    float* accbuf    = (float*)carve(4);

    // zero what must be zero every call (harness does not re-poison between replays)
    hipMemsetAsync(cnt,    0, (size_t)N_NODES * 4, stream);
    hipMemsetAsync(cursor, 0, (size_t)N_NODES * 4, stream);
    hipMemsetAsync(accbuf, 0, 4, stream);

    const int TB = 256;
    const int EB = (N_EDGES + TB - 1) / TB;
    const int NBn = (N_NODES + TB - 1) / TB;

    count_deg<<<EB, TB, 0, stream>>>(ei, cnt);
    calc_dis<<<NBn, TB, 0, stream>>>(cnt, dis);
    scan_counts<<<1, 1024, 0, stream>>>(cnt, row_start);
    fill_csr<<<EB, TB, 0, stream>>>(ei, row_start, cursor, dis, srcs, wn);

    // layer 1: aggregate x (A_hat x), then GEMM (+b1, relu) -> h1 in bufB
    agg_x<<<N_NODES, 128, 0, stream>>>(x, dis, row_start, srcs, wn, bufA);
    {
        dim3 grid((N_NODES + 63) / 64, HID / 128);
        gemm64x128<true><<<grid, 256, 0, stream>>>(bufA, W1, b1, bufB,
                                                   N_NODES, HID, IN_DIM);
    }
    // layer 2: GEMM h1 @ W2 -> G in bufA, then aggregate + bias + relu + pool + dot
    {
        dim3 grid((N_NODES + 63) / 64, HID2 / 128);
        gemm64x128<false><<<grid, 256, 0, stream>>>(bufB, W2, nullptr, bufA,
                                                    N_NODES, HID2, HID);
    }
    agg_g_pool<<<2048, 128, 0, stream>>>(bufA, dis, row_start, srcs, wn, b2, Wfc, accbuf);
    finalize<<<1, 1, 0, stream>>>(accbuf, bfc, out);
}

// Round 3
// 337.402 us; speedup vs baseline: 1.5231x; 1.5231x over previous
//
#include <hip/hip_runtime.h>
#include <hip/hip_bf16.h>

// Problem constants (match reference setup_inputs)
#define N_NODES 50000
#define N_EDGES 800000
#define IN_DIM  128
#define HID     256
#define HID2    128   // HID/2

// ---- bf16 helpers (manual, RNE) -------------------------------------------
static __device__ __forceinline__ unsigned f2bf(float f) {
    unsigned u = __float_as_uint(f);
    return (u + 0x7FFFu + ((u >> 16) & 1u)) >> 16;   // round-to-nearest-even
}
static __device__ __forceinline__ float bflo(unsigned u) { return __uint_as_float(u << 16); }
static __device__ __forceinline__ float bfhi(unsigned u) { return __uint_as_float(u & 0xFFFF0000u); }

// ---------------------------------------------------------------------------
// CSR build. edge_index is int32 per harness contract: [src[0..E), dst[0..E)]
// ---------------------------------------------------------------------------
__global__ void count_deg(const int* __restrict__ ei, int* __restrict__ cnt) {
    int e = blockIdx.x * blockDim.x + threadIdx.x;
    if (e < N_EDGES) atomicAdd(&cnt[ei[N_EDGES + e]], 1);
}

__global__ void calc_dis(const int* __restrict__ cnt, float* __restrict__ dis) {
    int i = blockIdx.x * blockDim.x + threadIdx.x;
    if (i < N_NODES) dis[i] = rsqrtf((float)(cnt[i] + 1));  // +1 self-loop
}

// single-block scan, wave-shfl based (3 barriers per 1024-chunk)
__global__ __launch_bounds__(1024)
void scan_counts(const int* __restrict__ cnt, int* __restrict__ row_start) {
    __shared__ int wsum[16];
    __shared__ int ctot;
    int tid = threadIdx.x, lane = tid & 63, wid = tid >> 6;
    int carry = 0;
    for (int base = 0; base < N_NODES; base += 1024) {
        int i = base + tid;
        int v = (i < N_NODES) ? cnt[i] : 0;
        int incl = v;
#pragma unroll
        for (int off = 1; off < 64; off <<= 1) {
            int t = __shfl_up(incl, off, 64);
            if (lane >= off) incl += t;
        }
        if (lane == 63) wsum[wid] = incl;
        __syncthreads();
        if (wid == 0 && lane < 16) {
            int s = wsum[lane];
            int si = s;
#pragma unroll
            for (int off = 1; off < 16; off <<= 1) {
                int t = __shfl_up(si, off, 16);
                if (lane >= off) si += t;
            }
            wsum[lane] = si - s;            // exclusive wave offset
            if (lane == 15) ctot = si;      // chunk total
        }
        __syncthreads();
        if (i < N_NODES) row_start[i] = carry + wsum[wid] + incl - v;
        carry += ctot;
        __syncthreads();                    // protect wsum/ctot before next chunk
    }
    if (tid == 0) row_start[N_NODES] = carry;
}

__global__ void fill_csr(const int* __restrict__ ei,
                         const int* __restrict__ row_start,
                         int* __restrict__ cursor,
                         const float* __restrict__ dis,
                         int* __restrict__ srcs, float* __restrict__ wn) {
    int e = blockIdx.x * blockDim.x + threadIdx.x;
    if (e < N_EDGES) {
        int s = ei[e];
        int d = ei[N_EDGES + e];
        int slot = row_start[d] + atomicAdd(&cursor[d], 1);
        srcs[slot] = s;
        wn[slot] = dis[s] * dis[d];
    }
}

// ---------------------------------------------------------------------------
// Pack x (f32) -> bf16 pairs (one uint per 2 cols). 1.6M float4 -> uint2.
// ---------------------------------------------------------------------------
__global__ __launch_bounds__(256)
void pack_x(const float* __restrict__ in, unsigned* __restrict__ out) {
    int t = blockIdx.x * 256 + threadIdx.x;          // grid sized exactly
    float4 v = ((const float4*)in)[t];
    uint2 p;
    p.x = f2bf(v.x) | (f2bf(v.y) << 16);
    p.y = f2bf(v.z) | (f2bf(v.w) << 16);
    ((uint2*)out)[t] = p;
}

// ---------------------------------------------------------------------------
// Aggregation 1 (bf16 gather): out[i,:] = dis[i]^2*X[i,:] + sum_e wn*X[src,:]
// 256-thread blocks = 4 waves = 4 nodes; lane owns a bf16 pair (2 cols).
// ---------------------------------------------------------------------------
__global__ __launch_bounds__(256)
void agg_x_bf16(const unsigned* __restrict__ Xb, const float* __restrict__ dis,
                const int* __restrict__ rs, const int* __restrict__ srcs,
                const float* __restrict__ wn, float* __restrict__ out) {
    int wid = threadIdx.x >> 6, lane = threadIdx.x & 63;
    int i = blockIdx.x * 4 + wid;
    if (i >= N_NODES) return;
    float di = dis[i];
    float sc = di * di;
    unsigned sv = Xb[(size_t)i * 64 + lane];
    float a0 = sc * bflo(sv), a1 = sc * bfhi(sv);
    int e = rs[i], e1 = rs[i + 1];
    for (; e + 3 < e1; e += 4) {
        int s0 = srcs[e], s1 = srcs[e + 1], s2 = srcs[e + 2], s3 = srcs[e + 3];
        float w0 = wn[e], w1 = wn[e + 1], w2 = wn[e + 2], w3 = wn[e + 3];
        unsigned v0 = Xb[(size_t)s0 * 64 + lane];
        unsigned v1 = Xb[(size_t)s1 * 64 + lane];
        unsigned v2 = Xb[(size_t)s2 * 64 + lane];
        unsigned v3 = Xb[(size_t)s3 * 64 + lane];
        a0 += w0 * bflo(v0); a1 += w0 * bfhi(v0);
        a0 += w1 * bflo(v1); a1 += w1 * bfhi(v1);
        a0 += w2 * bflo(v2); a1 += w2 * bfhi(v2);
        a0 += w3 * bflo(v3); a1 += w3 * bfhi(v3);
    }
    for (; e < e1; ++e) {
        int s = srcs[e]; float w = wn[e];
        unsigned v = Xb[(size_t)s * 64 + lane];
        a0 += w * bflo(v); a1 += w * bfhi(v);
    }
    *(float2*)&out[(size_t)i * IN_DIM + lane * 2] = make_float2(a0, a1);
}

// ---------------------------------------------------------------------------
// Aggregation 2 (bf16 gather) fused bias+ReLU+dot(Wfc) -> pernode scalar
// ---------------------------------------------------------------------------
__global__ __launch_bounds__(256)
void agg_g_pool_bf16(const unsigned* __restrict__ Gb, const float* __restrict__ dis,
                     const int* __restrict__ rs, const int* __restrict__ srcs,
                     const float* __restrict__ wn, const float* __restrict__ b2,
                     const float* __restrict__ wfc, float* __restrict__ pernode) {
    int wid = threadIdx.x >> 6, lane = threadIdx.x & 63;
    int i = blockIdx.x * 4 + wid;
    if (i >= N_NODES) return;
    float di = dis[i];
    float sc = di * di;
    unsigned sv = Gb[(size_t)i * 64 + lane];
    float a0 = sc * bflo(sv), a1 = sc * bfhi(sv);
    int e = rs[i], e1 = rs[i + 1];
    for (; e + 3 < e1; e += 4) {
        int s0 = srcs[e], s1 = srcs[e + 1], s2 = srcs[e + 2], s3 = srcs[e + 3];
        float w0 = wn[e], w1 = wn[e + 1], w2 = wn[e + 2], w3 = wn[e + 3];
        unsigned v0 = Gb[(size_t)s0 * 64 + lane];
        unsigned v1 = Gb[(size_t)s1 * 64 + lane];
        unsigned v2 = Gb[(size_t)s2 * 64 + lane];
        unsigned v3 = Gb[(size_t)s3 * 64 + lane];
        a0 += w0 * bflo(v0); a1 += w0 * bfhi(v0);
        a0 += w1 * bflo(v1); a1 += w1 * bfhi(v1);
        a0 += w2 * bflo(v2); a1 += w2 * bfhi(v2);
        a0 += w3 * bflo(v3); a1 += w3 * bfhi(v3);
    }
    for (; e < e1; ++e) {
        int s = srcs[e]; float w = wn[e];
        unsigned v = Gb[(size_t)s * 64 + lane];
        a0 += w * bflo(v); a1 += w * bfhi(v);
    }
    int c0 = lane * 2;
    float r = fmaxf(a0 + b2[c0], 0.f) * wfc[c0]
            + fmaxf(a1 + b2[c0 + 1], 0.f) * wfc[c0 + 1];
#pragma unroll
    for (int off = 32; off > 0; off >>= 1) r += __shfl_down(r, off, 64);
    if (lane == 0) pernode[i] = r;
}

__global__ __launch_bounds__(256)
void reduce_pernode(const float* __restrict__ pn, float* __restrict__ accbuf) {
    __shared__ float red[256];
    float s = 0.f;
    for (int i = blockIdx.x * 256 + threadIdx.x; i < N_NODES; i += gridDim.x * 256)
        s += pn[i];
    red[threadIdx.x] = s;
    __syncthreads();
    for (int off = 128; off > 0; off >>= 1) {
        if (threadIdx.x < off) red[threadIdx.x] += red[threadIdx.x + off];
        __syncthreads();
    }
    if (threadIdx.x == 0) atomicAdd(accbuf, red[0]);
}

__global__ void finalize(const float* __restrict__ accbuf,
                         const float* __restrict__ bfc, float* __restrict__ out) {
    out[0] = accbuf[0] * (1.0f / (float)N_NODES) + bfc[0];
}

// ---------------------------------------------------------------------------
// fp32 GEMM: C[M,N] = A[M,K] @ B[K,N]  (+bias+relu), f32 out  (layer 1)
// BM=64, BN=128, BK=32, 256 threads, 4x8 micro-tile
// ---------------------------------------------------------------------------
__global__ __launch_bounds__(256)
void gemm_f32out(const float* __restrict__ A, const float* __restrict__ B,
                 const float* __restrict__ bias, float* __restrict__ C,
                 int M, int N, int K) {
    __shared__ float As[64][33];
    __shared__ float Bs[32][128];

    int tid = threadIdx.x;
    int row0 = blockIdx.x * 64;
    int col0 = blockIdx.y * 128;
    int ty = tid >> 4;
    int tx = tid & 15;

    float acc[4][8];
#pragma unroll
    for (int i = 0; i < 4; ++i)
#pragma unroll
        for (int j = 0; j < 8; ++j) acc[i][j] = 0.f;

    int arow = tid >> 3;
    int akc  = (tid & 7) * 4;
    int brow = tid >> 5;
    int bcol = (tid & 31) * 4;

    for (int k0 = 0; k0 < K; k0 += 32) {
#pragma unroll
        for (int r = 0; r < 2; ++r) {
            int m = arow + r * 32;
            int grow = row0 + m;
            float4 v = make_float4(0.f, 0.f, 0.f, 0.f);
            if (grow < M) v = *(const float4*)&A[(size_t)grow * K + k0 + akc];
            As[m][akc + 0] = v.x; As[m][akc + 1] = v.y;
            As[m][akc + 2] = v.z; As[m][akc + 3] = v.w;
        }
#pragma unroll
        for (int r = 0; r < 4; ++r) {
            int kr = brow + r * 8;
            *(float4*)&Bs[kr][bcol] = *(const float4*)&B[(size_t)(k0 + kr) * N + col0 + bcol];
        }
        __syncthreads();
#pragma unroll
        for (int kk = 0; kk < 32; ++kk) {
            float a0 = As[ty * 4 + 0][kk];
            float a1 = As[ty * 4 + 1][kk];
            float a2 = As[ty * 4 + 2][kk];
            float a3 = As[ty * 4 + 3][kk];
            float4 bl = *(const float4*)&Bs[kk][tx * 4];
            float4 bh = *(const float4*)&Bs[kk][64 + tx * 4];
            acc[0][0] += a0 * bl.x; acc[0][1] += a0 * bl.y; acc[0][2] += a0 * bl.z; acc[0][3] += a0 * bl.w;
            acc[0][4] += a0 * bh.x; acc[0][5] += a0 * bh.y; acc[0][6] += a0 * bh.z; acc[0][7] += a0 * bh.w;
            acc[1][0] += a1 * bl.x; acc[1][1] += a1 * bl.y; acc[1][2] += a1 * bl.z; acc[1][3] += a1 * bl.w;
            acc[1][4] += a1 * bh.x; acc[1][5] += a1 * bh.y; acc[1][6] += a1 * bh.z; acc[1][7] += a1 * bh.w;
            acc[2][0] += a2 * bl.x; acc[2][1] += a2 * bl.y; acc[2][2] += a2 * bl.z; acc[2][3] += a2 * bl.w;
            acc[2][4] += a2 * bh.x; acc[2][5] += a2 * bh.y; acc[2][6] += a2 * bh.z; acc[2][7] += a2 * bh.w;
            acc[3][0] += a3 * bl.x; acc[3][1] += a3 * bl.y; acc[3][2] += a3 * bl.z; acc[3][3] += a3 * bl.w;
            acc[3][4] += a3 * bh.x; acc[3][5] += a3 * bh.y; acc[3][6] += a3 * bh.z; acc[3][7] += a3 * bh.w;
        }
        __syncthreads();
    }

    float blo[4], bhi[4];
#pragma unroll
    for (int j = 0; j < 4; ++j) {
        blo[j] = bias[col0 + tx * 4 + j];
        bhi[j] = bias[col0 + 64 + tx * 4 + j];
    }
#pragma unroll
    for (int i = 0; i < 4; ++i) {
        int grow = row0 + ty * 4 + i;
        if (grow < M) {
            float4 lo, hi;
            lo.x = fmaxf(acc[i][0] + blo[0], 0.f); lo.y = fmaxf(acc[i][1] + blo[1], 0.f);
            lo.z = fmaxf(acc[i][2] + blo[2], 0.f); lo.w = fmaxf(acc[i][3] + blo[3], 0.f);
            hi.x = fmaxf(acc[i][4] + bhi[0], 0.f); hi.y = fmaxf(acc[i][5] + bhi[1], 0.f);
            hi.z = fmaxf(acc[i][6] + bhi[2], 0.f); hi.w = fmaxf(acc[i][7] + bhi[3], 0.f);
            *(float4*)&C[(size_t)grow * N + col0 + tx * 4] = lo;
            *(float4*)&C[(size_t)grow * N + col0 + 64 + tx * 4] = hi;
        }
    }
}

// ---------------------------------------------------------------------------
// fp32 GEMM, bf16 packed output (layer 2: G = h1 @ W2, no bias/relu here)
// ---------------------------------------------------------------------------
__global__ __launch_bounds__(256)
void gemm_bf16out(const float* __restrict__ A, const float* __restrict__ B,
                  unsigned* __restrict__ C, int M, int N, int K) {
    __shared__ float As[64][33];
    __shared__ float Bs[32][128];

    int tid = threadIdx.x;
    int row0 = blockIdx.x * 64;
    int col0 = blockIdx.y * 128;
    int ty = tid >> 4;
    int tx = tid & 15;

    float acc[4][8];
#pragma unroll
    for (int i = 0; i < 4; ++i)
#pragma unroll
        for (int j = 0; j < 8; ++j) acc[i][j] = 0.f;

    int arow = tid >> 3;
    int akc  = (tid & 7) * 4;
    int brow = tid >> 5;
    int bcol = (tid & 31) * 4;

    for (int k0 = 0; k0 < K; k0 += 32) {
#pragma unroll
        for (int r = 0; r < 2; ++r) {
            int m = arow + r * 32;
            int grow = row0 + m;
            float4 v = make_float4(0.f, 0.f, 0.f, 0.f);
            if (grow < M) v = *(const float4*)&A[(size_t)grow * K + k0 + akc];
            As[m][akc + 0] = v.x; As[m][akc + 1] = v.y;
            As[m][akc + 2] = v.z; As[m][akc + 3] = v.w;
        }
#pragma unroll
        for (int r = 0; r < 4; ++r) {
            int kr = brow + r * 8;
            *(float4*)&Bs[kr][bcol] = *(const float4*)&B[(size_t)(k0 + kr) * N + col0 + bcol];
        }
        __syncthreads();
#pragma unroll
        for (int kk = 0; kk < 32; ++kk) {
            float a0 = As[ty * 4 + 0][kk];
            float a1 = As[ty * 4 + 1][kk];
            float a2 = As[ty * 4 + 2][kk];
            float a3 = As[ty * 4 + 3][kk];
            float4 bl = *(const float4*)&Bs[kk][tx * 4];
            float4 bh = *(const float4*)&Bs[kk][64 + tx * 4];
            acc[0][0] += a0 * bl.x; acc[0][1] += a0 * bl.y; acc[0][2] += a0 * bl.z; acc[0][3] += a0 * bl.w;
            acc[0][4] += a0 * bh.x; acc[0][5] += a0 * bh.y; acc[0][6] += a0 * bh.z; acc[0][7] += a0 * bh.w;
            acc[1][0] += a1 * bl.x; acc[1][1] += a1 * bl.y; acc[1][2] += a1 * bl.z; acc[1][3] += a1 * bl.w;
            acc[1][4] += a1 * bh.x; acc[1][5] += a1 * bh.y; acc[1][6] += a1 * bh.z; acc[1][7] += a1 * bh.w;
            acc[2][0] += a2 * bl.x; acc[2][1] += a2 * bl.y; acc[2][2] += a2 * bl.z; acc[2][3] += a2 * bl.w;
            acc[2][4] += a2 * bh.x; acc[2][5] += a2 * bh.y; acc[2][6] += a2 * bh.z; acc[2][7] += a2 * bh.w;
            acc[3][0] += a3 * bl.x; acc[3][1] += a3 * bl.y; acc[3][2] += a3 * bl.z; acc[3][3] += a3 * bl.w;
            acc[3][4] += a3 * bh.x; acc[3][5] += a3 * bh.y; acc[3][6] += a3 * bh.z; acc[3][7] += a3 * bh.w;
        }
        __syncthreads();
    }

    int nw = N >> 1;   // row stride in uints
#pragma unroll
    for (int i = 0; i < 4; ++i) {
        int grow = row0 + ty * 4 + i;
        if (grow < M) {
            uint2 lo, hi;
            lo.x = f2bf(acc[i][0]) | (f2bf(acc[i][1]) << 16);
            lo.y = f2bf(acc[i][2]) | (f2bf(acc[i][3]) << 16);
            hi.x = f2bf(acc[i][4]) | (f2bf(acc[i][5]) << 16);
            hi.y = f2bf(acc[i][6]) | (f2bf(acc[i][7]) << 16);
            *(uint2*)&C[(size_t)grow * nw + ((col0 + tx * 4) >> 1)] = lo;
            *(uint2*)&C[(size_t)grow * nw + ((col0 + 64 + tx * 4) >> 1)] = hi;
        }
    }
}

// ---------------------------------------------------------------------------
// launcher
// ---------------------------------------------------------------------------
extern "C" void kernel_launch(void* const* d_in, const int* in_sizes, int n_in,
                              void* d_out, int out_size, void* d_ws, size_t ws_size,
                              hipStream_t stream) {
    const float* x   = (const float*)d_in[0];
    const int*   ei  = (const int*)d_in[1];     // int32 per harness contract
    const float* W1  = (const float*)d_in[2];
    const float* b1  = (const float*)d_in[3];
    const float* W2  = (const float*)d_in[4];
    const float* b2  = (const float*)d_in[5];
    const float* Wfc = (const float*)d_in[6];
    const float* bfc = (const float*)d_in[7];
    float* out = (float*)d_out;

    char* ws = (char*)d_ws;
    size_t off = 0;
    auto carve = [&](size_t bytes) {
        void* p = ws + off;
        off += (bytes + 255) & ~(size_t)255;
        return p;
    };
    int*   cnt       = (int*)  carve((size_t)N_NODES * 4);
    int*   row_start = (int*)  carve((size_t)(N_NODES + 1) * 4);
    int*   cursor    = (int*)  carve((size_t)N_NODES * 4);
    float* dis       = (float*)carve((size_t)N_NODES * 4);
    int*   srcs      = (int*)  carve((size_t)N_EDGES * 4);
    float* wn        = (float*)carve((size_t)N_EDGES * 4);
    float* bufA      = (float*)carve((size_t)N_NODES * IN_DIM * 4);   // aggX f32; later Gb (bf16) overlays
    float* bufB      = (float*)carve((size_t)N_NODES * HID * 4);      // Xb (bf16) overlays; later h1 f32
    float* pernode   = (float*)carve((size_t)N_NODES * 4);
    float* accbuf    = (float*)carve(4);

    unsigned* Xb = (unsigned*)bufB;   // 12.8 MB, dead before gemm1 writes h1
    unsigned* Gb = (unsigned*)bufA;   // 12.8 MB, aggX dead after gemm1

    hipMemsetAsync(cnt,    0, (size_t)N_NODES * 4, stream);
    hipMemsetAsync(cursor, 0, (size_t)N_NODES * 4, stream);
    hipMemsetAsync(accbuf, 0, 4, stream);

    const int TB = 256;
    const int EB = (N_EDGES + TB - 1) / TB;
    const int NBn = (N_NODES + TB - 1) / TB;

    count_deg<<<EB, TB, 0, stream>>>(ei, cnt);
    calc_dis<<<NBn, TB, 0, stream>>>(cnt, dis);
    scan_counts<<<1, 1024, 0, stream>>>(cnt, row_start);
    fill_csr<<<EB, TB, 0, stream>>>(ei, row_start, cursor, dis, srcs, wn);

    // pack x to bf16 (exact grid: 1.6M float4s)
    pack_x<<<(N_NODES * IN_DIM / 4) / 256, 256, 0, stream>>>(x, Xb);

    // layer 1: aggregate x (bf16 gather) -> bufA f32; GEMM +b1+relu -> bufB f32
    agg_x_bf16<<<(N_NODES + 3) / 4, 256, 0, stream>>>(Xb, dis, row_start, srcs, wn, bufA);
    {
        dim3 grid((N_NODES + 63) / 64, HID / 128);
        gemm_f32out<<<grid, 256, 0, stream>>>(bufA, W1, b1, bufB, N_NODES, HID, IN_DIM);
    }
    // layer 2: GEMM h1 @ W2 -> Gb bf16; aggregate (bf16 gather)+b2+relu+dot -> pernode
    {
        dim3 grid((N_NODES + 63) / 64, HID2 / 128);
        gemm_bf16out<<<grid, 256, 0, stream>>>(bufB, W2, Gb, N_NODES, HID2, HID);
    }
    agg_g_pool_bf16<<<(N_NODES + 3) / 4, 256, 0, stream>>>(Gb, dis, row_start, srcs, wn,
                                                           b2, Wfc, pernode);
    reduce_pernode<<<32, 256, 0, stream>>>(pernode, accbuf);
    finalize<<<1, 1, 0, stream>>>(accbuf, bfc, out);
}

// Round 6
// 265.184 us; speedup vs baseline: 1.9378x; 1.2723x over previous
//
#include <hip/hip_runtime.h>
#include <hip/hip_bf16.h>

// Problem constants (match reference setup_inputs)
#define N_NODES 50000
#define N_EDGES 800000
#define IN_DIM  128
#define HID     256
#define HID2    128   // HID/2

using bf16x8 = __attribute__((ext_vector_type(8))) short;
using f32x4  = __attribute__((ext_vector_type(4))) float;

// ---- bf16 helpers (manual, RNE) -------------------------------------------
static __device__ __forceinline__ unsigned f2bf(float f) {
    unsigned u = __float_as_uint(f);
    return (u + 0x7FFFu + ((u >> 16) & 1u)) >> 16;   // round-to-nearest-even
}
static __device__ __forceinline__ float bflo(unsigned u) { return __uint_as_float(u << 16); }
static __device__ __forceinline__ float bfhi(unsigned u) { return __uint_as_float(u & 0xFFFF0000u); }

// ---------------------------------------------------------------------------
// CSR build. edge_index is int32 per harness contract: [src[0..E), dst[0..E)]
// ---------------------------------------------------------------------------
__global__ void count_deg(const int* __restrict__ ei, int* __restrict__ cnt) {
    int e = blockIdx.x * blockDim.x + threadIdx.x;
    if (e < N_EDGES) atomicAdd(&cnt[ei[N_EDGES + e]], 1);
}

__global__ void calc_dis(const int* __restrict__ cnt, float* __restrict__ dis) {
    int i = blockIdx.x * blockDim.x + threadIdx.x;
    if (i < N_NODES) dis[i] = rsqrtf((float)(cnt[i] + 1));  // +1 self-loop
}

// single-block scan, wave-shfl based
__global__ __launch_bounds__(1024)
void scan_counts(const int* __restrict__ cnt, int* __restrict__ row_start) {
    __shared__ int wsum[16];
    __shared__ int ctot;
    int tid = threadIdx.x, lane = tid & 63, wid = tid >> 6;
    int carry = 0;
    for (int base = 0; base < N_NODES; base += 1024) {
        int i = base + tid;
        int v = (i < N_NODES) ? cnt[i] : 0;
        int incl = v;
#pragma unroll
        for (int off = 1; off < 64; off <<= 1) {
            int t = __shfl_up(incl, off, 64);
            if (lane >= off) incl += t;
        }
        if (lane == 63) wsum[wid] = incl;
        __syncthreads();
        if (wid == 0 && lane < 16) {
            int s = wsum[lane];
            int si = s;
#pragma unroll
            for (int off = 1; off < 16; off <<= 1) {
                int t = __shfl_up(si, off, 16);
                if (lane >= off) si += t;
            }
            wsum[lane] = si - s;            // exclusive wave offset
            if (lane == 15) ctot = si;      // chunk total
        }
        __syncthreads();
        if (i < N_NODES) row_start[i] = carry + wsum[wid] + incl - v;
        carry += ctot;
        __syncthreads();
    }
    if (tid == 0) row_start[N_NODES] = carry;
}

__global__ void fill_csr(const int* __restrict__ ei,
                         const int* __restrict__ row_start,
                         int* __restrict__ cursor,
                         const float* __restrict__ dis,
                         int* __restrict__ srcs, float* __restrict__ wn) {
    int e = blockIdx.x * blockDim.x + threadIdx.x;
    if (e < N_EDGES) {
        int s = ei[e];
        int d = ei[N_EDGES + e];
        int slot = row_start[d] + atomicAdd(&cursor[d], 1);
        srcs[slot] = s;
        wn[slot] = dis[s] * dis[d];
    }
}

// ---------------------------------------------------------------------------
// Pack x (f32) -> bf16 pairs. 1.6M float4 -> uint2. Grid exact.
// ---------------------------------------------------------------------------
__global__ __launch_bounds__(256)
void pack_x(const float* __restrict__ in, unsigned* __restrict__ out) {
    int t = blockIdx.x * 256 + threadIdx.x;
    float4 v = ((const float4*)in)[t];
    uint2 p;
    p.x = f2bf(v.x) | (f2bf(v.y) << 16);
    p.y = f2bf(v.z) | (f2bf(v.w) << 16);
    ((uint2*)out)[t] = p;
}

// Pack W[K][N] f32 -> WT[N][K] bf16 (transposed). total = K*N threads.
__global__ __launch_bounds__(256)
void pack_wt(const float* __restrict__ W, unsigned short* __restrict__ WT,
             int K, int N) {
    int t = blockIdx.x * 256 + threadIdx.x;
    if (t < K * N) {
        int n = t / K, k = t - n * K;
        WT[t] = (unsigned short)f2bf(W[(size_t)k * N + n]);
    }
}

// ---------------------------------------------------------------------------
// Aggregation 1 (bf16 gather -> bf16 out): Ab[i,:] = dis^2*X[i,:] + sum wn*X[src,:]
// ---------------------------------------------------------------------------
__global__ __launch_bounds__(256)
void agg_x_bf16(const unsigned* __restrict__ Xb, const float* __restrict__ dis,
                const int* __restrict__ rs, const int* __restrict__ srcs,
                const float* __restrict__ wn, unsigned* __restrict__ Ab) {
    int wid = threadIdx.x >> 6, lane = threadIdx.x & 63;
    int i = blockIdx.x * 4 + wid;
    if (i >= N_NODES) return;
    float di = dis[i];
    float sc = di * di;
    unsigned sv = Xb[(size_t)i * 64 + lane];
    float a0 = sc * bflo(sv), a1 = sc * bfhi(sv);
    int e = rs[i], e1 = rs[i + 1];
    for (; e + 3 < e1; e += 4) {
        int s0 = srcs[e], s1 = srcs[e + 1], s2 = srcs[e + 2], s3 = srcs[e + 3];
        float w0 = wn[e], w1 = wn[e + 1], w2 = wn[e + 2], w3 = wn[e + 3];
        unsigned v0 = Xb[(size_t)s0 * 64 + lane];
        unsigned v1 = Xb[(size_t)s1 * 64 + lane];
        unsigned v2 = Xb[(size_t)s2 * 64 + lane];
        unsigned v3 = Xb[(size_t)s3 * 64 + lane];
        a0 += w0 * bflo(v0); a1 += w0 * bfhi(v0);
        a0 += w1 * bflo(v1); a1 += w1 * bfhi(v1);
        a0 += w2 * bflo(v2); a1 += w2 * bfhi(v2);
        a0 += w3 * bflo(v3); a1 += w3 * bfhi(v3);
    }
    for (; e < e1; ++e) {
        int s = srcs[e]; float w = wn[e];
        unsigned v = Xb[(size_t)s * 64 + lane];
        a0 += w * bflo(v); a1 += w * bfhi(v);
    }
    Ab[(size_t)i * 64 + lane] = f2bf(a0) | (f2bf(a1) << 16);
}

// ---------------------------------------------------------------------------
// Aggregation 2 (bf16 gather) fused bias+ReLU+dot(Wfc) -> pernode scalar
// ---------------------------------------------------------------------------
__global__ __launch_bounds__(256)
void agg_g_pool_bf16(const unsigned* __restrict__ Gb, const float* __restrict__ dis,
                     const int* __restrict__ rs, const int* __restrict__ srcs,
                     const float* __restrict__ wn, const float* __restrict__ b2,
                     const float* __restrict__ wfc, float* __restrict__ pernode) {
    int wid = threadIdx.x >> 6, lane = threadIdx.x & 63;
    int i = blockIdx.x * 4 + wid;
    if (i >= N_NODES) return;
    float di = dis[i];
    float sc = di * di;
    unsigned sv = Gb[(size_t)i * 64 + lane];
    float a0 = sc * bflo(sv), a1 = sc * bfhi(sv);
    int e = rs[i], e1 = rs[i + 1];
    for (; e + 3 < e1; e += 4) {
        int s0 = srcs[e], s1 = srcs[e + 1], s2 = srcs[e + 2], s3 = srcs[e + 3];
        float w0 = wn[e], w1 = wn[e + 1], w2 = wn[e + 2], w3 = wn[e + 3];
        unsigned v0 = Gb[(size_t)s0 * 64 + lane];
        unsigned v1 = Gb[(size_t)s1 * 64 + lane];
        unsigned v2 = Gb[(size_t)s2 * 64 + lane];
        unsigned v3 = Gb[(size_t)s3 * 64 + lane];
        a0 += w0 * bflo(v0); a1 += w0 * bfhi(v0);
        a0 += w1 * bflo(v1); a1 += w1 * bfhi(v1);
        a0 += w2 * bflo(v2); a1 += w2 * bfhi(v2);
        a0 += w3 * bflo(v3); a1 += w3 * bfhi(v3);
    }
    for (; e < e1; ++e) {
        int s = srcs[e]; float w = wn[e];
        unsigned v = Gb[(size_t)s * 64 + lane];
        a0 += w * bflo(v); a1 += w * bfhi(v);
    }
    int c0 = lane * 2;
    float r = fmaxf(a0 + b2[c0], 0.f) * wfc[c0]
            + fmaxf(a1 + b2[c0 + 1], 0.f) * wfc[c0 + 1];
#pragma unroll
    for (int off = 32; off > 0; off >>= 1) r += __shfl_down(r, off, 64);
    if (lane == 0) pernode[i] = r;
}

__global__ __launch_bounds__(256)
void reduce_pernode(const float* __restrict__ pn, float* __restrict__ accbuf) {
    __shared__ float red[256];
    float s = 0.f;
    for (int i = blockIdx.x * 256 + threadIdx.x; i < N_NODES; i += gridDim.x * 256)
        s += pn[i];
    red[threadIdx.x] = s;
    __syncthreads();
    for (int off = 128; off > 0; off >>= 1) {
        if (threadIdx.x < off) red[threadIdx.x] += red[threadIdx.x + off];
        __syncthreads();
    }
    if (threadIdx.x == 0) atomicAdd(accbuf, red[0]);
}

__global__ void finalize(const float* __restrict__ accbuf,
                         const float* __restrict__ bfc, float* __restrict__ out) {
    out[0] = accbuf[0] * (1.0f / (float)N_NODES) + bfc[0];
}

// ---------------------------------------------------------------------------
// bf16 MFMA GEMM: C[M,N] = A[M,K] @ WT[N,K]^T, f32 accum, bf16 out.
// BM=64, BN=128, BK=32; 256 threads = 4 waves, wave w -> 32x64 quadrant.
// LDS fragment-contiguous layout [kb][row][8] -> conflict-free ds_read_b128.
// mfma_f32_16x16x32_bf16: A lane l holds row=l&15, k=(l>>4)*8+j;
//                         B lane l holds col=l&15, k=(l>>4)*8+j;
//                         D lane l reg r -> col=l&15, row=(l>>4)*4+r  (m89)
// ---------------------------------------------------------------------------
template<bool BIAS_RELU>
__global__ __launch_bounds__(256)
void gemm_mfma(const unsigned short* __restrict__ A,   // [M][K] bf16
               const unsigned short* __restrict__ WT,  // [N][K] bf16
               const float* __restrict__ bias,         // [N] (if BIAS_RELU)
               unsigned short* __restrict__ C,         // [M][N] bf16
               int M, int N, int K) {
    __shared__ __align__(16) unsigned short Asl[4 * 64 * 8];    // 4KB
    __shared__ __align__(16) unsigned short Bsl[4 * 128 * 8];   // 8KB

    int tid = threadIdx.x;
    int lane = tid & 63, w = tid >> 6;
    int wr = w >> 1, wc = w & 1;
    int row0 = blockIdx.x * 64;
    int col0 = blockIdx.y * 128;

    f32x4 acc[2][4];
#pragma unroll
    for (int i = 0; i < 2; ++i)
#pragma unroll
        for (int j = 0; j < 4; ++j) acc[i][j] = (f32x4){0.f, 0.f, 0.f, 0.f};

    // staging addresses (linear-in-tid LDS destinations)
    int arow = min(row0 + (tid & 63), M - 1);      // clamp: OOB rows read valid mem
    const unsigned short* agp = A + (size_t)arow * K + (tid >> 6) * 8;
    const unsigned short* bgp0 = WT + (size_t)(col0 + (tid & 127)) * K + (tid >> 7) * 8;
    const unsigned short* bgp1 = bgp0 + 16;        // kb += 2

    const bf16x8* Av = (const bf16x8*)Asl;
    const bf16x8* Bv = (const bf16x8*)Bsl;
    int aidx = (lane >> 4) * 64 + wr * 32 + (lane & 15);    // + fm*16
    int bidx = (lane >> 4) * 128 + wc * 64 + (lane & 15);   // + fn*16

    for (int k0 = 0; k0 < K; k0 += 32) {
        *(float4*)&Asl[tid * 8]         = *(const float4*)(agp + k0);
        *(float4*)&Bsl[tid * 8]         = *(const float4*)(bgp0 + k0);
        *(float4*)&Bsl[(tid + 256) * 8] = *(const float4*)(bgp1 + k0);
        __syncthreads();

        bf16x8 af[2], bf[4];
#pragma unroll
        for (int fm = 0; fm < 2; ++fm) af[fm] = Av[aidx + fm * 16];
#pragma unroll
        for (int fn = 0; fn < 4; ++fn) bf[fn] = Bv[bidx + fn * 16];
#pragma unroll
        for (int fm = 0; fm < 2; ++fm)
#pragma unroll
            for (int fn = 0; fn < 4; ++fn)
                acc[fm][fn] = __builtin_amdgcn_mfma_f32_16x16x32_bf16(
                    af[fm], bf[fn], acc[fm][fn], 0, 0, 0);
        __syncthreads();
    }

    // epilogue: D lane l reg r -> row=(l>>4)*4+r, col=l&15 within fragment
    float bv[4];
    if (BIAS_RELU) {
#pragma unroll
        for (int fn = 0; fn < 4; ++fn)
            bv[fn] = bias[col0 + wc * 64 + fn * 16 + (lane & 15)];
    }
#pragma unroll
    for (int fm = 0; fm < 2; ++fm) {
#pragma unroll
        for (int r = 0; r < 4; ++r) {
            int row = row0 + wr * 32 + fm * 16 + (lane >> 4) * 4 + r;
            if (row < M) {
#pragma unroll
                for (int fn = 0; fn < 4; ++fn) {
                    int col = col0 + wc * 64 + fn * 16 + (lane & 15);
                    float v = acc[fm][fn][r];
                    if (BIAS_RELU) v = fmaxf(v + bv[fn], 0.f);
                    C[(size_t)row * N + col] = (unsigned short)f2bf(v);
                }
            }
        }
    }
}

// ---------------------------------------------------------------------------
// launcher
// ---------------------------------------------------------------------------
extern "C" void kernel_launch(void* const* d_in, const int* in_sizes, int n_in,
                              void* d_out, int out_size, void* d_ws, size_t ws_size,
                              hipStream_t stream) {
    const float* x   = (const float*)d_in[0];
    const int*   ei  = (const int*)d_in[1];     // int32 per harness contract
    const float* W1  = (const float*)d_in[2];
    const float* b1  = (const float*)d_in[3];
    const float* W2  = (const float*)d_in[4];
    const float* b2  = (const float*)d_in[5];
    const float* Wfc = (const float*)d_in[6];
    const float* bfc = (const float*)d_in[7];
    float* out = (float*)d_out;

    char* ws = (char*)d_ws;
    size_t off = 0;
    auto carve = [&](size_t bytes) {
        void* p = ws + off;
        off += (bytes + 255) & ~(size_t)255;
        return p;
    };
    int*   cnt       = (int*)  carve((size_t)N_NODES * 4);
    int*   row_start = (int*)  carve((size_t)(N_NODES + 1) * 4);
    int*   cursor    = (int*)  carve((size_t)N_NODES * 4);
    float* dis       = (float*)carve((size_t)N_NODES * 4);
    int*   srcs      = (int*)  carve((size_t)N_EDGES * 4);
    float* wn        = (float*)carve((size_t)N_EDGES * 4);
    unsigned* Xb     = (unsigned*)carve((size_t)N_NODES * 64 * 4);        // x bf16
    unsigned* Ab     = (unsigned*)carve((size_t)N_NODES * 64 * 4);        // agg1 bf16
    unsigned short* h1b = (unsigned short*)carve((size_t)N_NODES * HID * 2);  // h1 bf16
    unsigned short* Gb  = (unsigned short*)carve((size_t)N_NODES * HID2 * 2); // G bf16
    unsigned short* WT1 = (unsigned short*)carve((size_t)HID * IN_DIM * 2);
    unsigned short* WT2 = (unsigned short*)carve((size_t)HID2 * HID * 2);
    float* pernode   = (float*)carve((size_t)N_NODES * 4);
    float* accbuf    = (float*)carve(4);

    hipMemsetAsync(cnt,    0, (size_t)N_NODES * 4, stream);
    hipMemsetAsync(cursor, 0, (size_t)N_NODES * 4, stream);
    hipMemsetAsync(accbuf, 0, 4, stream);

    const int TB = 256;
    const int EB = (N_EDGES + TB - 1) / TB;
    const int NBn = (N_NODES + TB - 1) / TB;

    count_deg<<<EB, TB, 0, stream>>>(ei, cnt);
    calc_dis<<<NBn, TB, 0, stream>>>(cnt, dis);
    scan_counts<<<1, 1024, 0, stream>>>(cnt, row_start);
    fill_csr<<<EB, TB, 0, stream>>>(ei, row_start, cursor, dis, srcs, wn);

    pack_x<<<(N_NODES * IN_DIM / 4) / 256, 256, 0, stream>>>(x, Xb);
    pack_wt<<<(IN_DIM * HID + 255) / 256, 256, 0, stream>>>(W1, WT1, IN_DIM, HID);
    pack_wt<<<(HID * HID2 + 255) / 256, 256, 0, stream>>>(W2, WT2, HID, HID2);

    // layer 1: aggregate x (bf16) -> Ab; MFMA GEMM +b1+relu -> h1b
    agg_x_bf16<<<(N_NODES + 3) / 4, 256, 0, stream>>>(Xb, dis, row_start, srcs, wn, Ab);
    {
        dim3 grid((N_NODES + 63) / 64, HID / 128);
        gemm_mfma<true><<<grid, 256, 0, stream>>>((const unsigned short*)Ab, WT1, b1,
                                                  h1b, N_NODES, HID, IN_DIM);
    }
    // layer 2: MFMA GEMM h1 @ W2 -> Gb; aggregate + b2 + relu + dot -> pernode
    {
        dim3 grid((N_NODES + 63) / 64, HID2 / 128);
        gemm_mfma<false><<<grid, 256, 0, stream>>>(h1b, WT2, nullptr,
                                                   Gb, N_NODES, HID2, HID);
    }
    agg_g_pool_bf16<<<(N_NODES + 3) / 4, 256, 0, stream>>>((const unsigned*)Gb, dis,
                                                           row_start, srcs, wn,
                                                           b2, Wfc, pernode);
    reduce_pernode<<<32, 256, 0, stream>>>(pernode, accbuf);
    finalize<<<1, 1, 0, stream>>>(accbuf, bfc, out);
}

// Round 7
// 197.043 us; speedup vs baseline: 2.6080x; 1.3458x over previous
//
#include <hip/hip_runtime.h>
#include <hip/hip_bf16.h>

// Problem constants (match reference setup_inputs)
#define N_NODES 50000
#define N_EDGES 800000
#define IN_DIM  128
#define HID     256
#define HID2    128   // HID/2
#define NSCAN   196   // ceil(N_NODES/256)

using bf16x8 = __attribute__((ext_vector_type(8))) short;
using f32x4  = __attribute__((ext_vector_type(4))) float;

// ---- bf16 helpers (manual, RNE) -------------------------------------------
static __device__ __forceinline__ unsigned f2bf(float f) {
    unsigned u = __float_as_uint(f);
    return (u + 0x7FFFu + ((u >> 16) & 1u)) >> 16;   // round-to-nearest-even
}
static __device__ __forceinline__ float bflo(unsigned u) { return __uint_as_float(u << 16); }
static __device__ __forceinline__ float bfhi(unsigned u) { return __uint_as_float(u & 0xFFFF0000u); }

// ---------------------------------------------------------------------------
// Graph build. edge_index int32: [src[0..E), dst[0..E)].
// out[i] = dis_i*(Xs[i] + sum_src Xs[src]) with Xs pre-scaled by dis -> no wn.
// ---------------------------------------------------------------------------
__global__ void count_ord(const int* __restrict__ ei, int* __restrict__ cnt,
                          int* __restrict__ ord) {
    int e = blockIdx.x * blockDim.x + threadIdx.x;
    if (e < N_EDGES) ord[e] = atomicAdd(&cnt[ei[N_EDGES + e]], 1);
}

// phase A: per-block (256-wide) exclusive scan + block partials + dis
__global__ __launch_bounds__(256)
void scanA(const int* __restrict__ cnt, int* __restrict__ rs_tmp,
           int* __restrict__ partials, float* __restrict__ dis) {
    __shared__ int ws[4], woff[4];
    int i = blockIdx.x * 256 + threadIdx.x;
    int lane = threadIdx.x & 63, wid = threadIdx.x >> 6;
    int v = (i < N_NODES) ? cnt[i] : 0;
    int incl = v;
#pragma unroll
    for (int off = 1; off < 64; off <<= 1) {
        int t = __shfl_up(incl, off, 64);
        if (lane >= off) incl += t;
    }
    if (lane == 63) ws[wid] = incl;
    __syncthreads();
    if (threadIdx.x == 0) {
        int a = 0;
#pragma unroll
        for (int k = 0; k < 4; ++k) { woff[k] = a; a += ws[k]; }
        partials[blockIdx.x] = a;
    }
    __syncthreads();
    if (i < N_NODES) {
        rs_tmp[i] = woff[wid] + incl - v;
        dis[i] = rsqrtf((float)(v + 1));
    }
}

// phase B: single block scans NSCAN partials -> exclusive offsets
__global__ __launch_bounds__(256)
void scanB(const int* __restrict__ partials, int* __restrict__ offs) {
    __shared__ int ws[4], woff[4];
    int t = threadIdx.x;
    int lane = t & 63, wid = t >> 6;
    int v = (t < NSCAN) ? partials[t] : 0;
    int incl = v;
#pragma unroll
    for (int off = 1; off < 64; off <<= 1) {
        int s = __shfl_up(incl, off, 64);
        if (lane >= off) incl += s;
    }
    if (lane == 63) ws[wid] = incl;
    __syncthreads();
    if (t == 0) {
        int a = 0;
#pragma unroll
        for (int k = 0; k < 4; ++k) { woff[k] = a; a += ws[k]; }
    }
    __syncthreads();
    if (t < NSCAN) offs[t] = woff[wid] + incl - v;
}

// phase C: add block offsets
__global__ __launch_bounds__(256)
void scanC(const int* __restrict__ rs_tmp, const int* __restrict__ offs,
           int* __restrict__ rs) {
    int i = blockIdx.x * 256 + threadIdx.x;
    if (i < N_NODES) rs[i] = rs_tmp[i] + offs[blockIdx.x];
    if (i == 0) rs[N_NODES] = N_EDGES;
}

__global__ void fill_csr(const int* __restrict__ ei, const int* __restrict__ rs,
                         const int* __restrict__ ord, int* __restrict__ srcs) {
    int e = blockIdx.x * blockDim.x + threadIdx.x;
    if (e < N_EDGES) {
        int d = ei[N_EDGES + e];
        srcs[rs[d] + ord[e]] = ei[e];
    }
}

// ---------------------------------------------------------------------------
// Pack x scaled by dis[row] -> bf16 pairs. t indexes float4s; row = t>>5.
// ---------------------------------------------------------------------------
__global__ __launch_bounds__(256)
void pack_x_scaled(const float* __restrict__ in, const float* __restrict__ dis,
                   unsigned* __restrict__ out) {
    int t = blockIdx.x * 256 + threadIdx.x;
    float d = dis[t >> 5];
    float4 v = ((const float4*)in)[t];
    uint2 p;
    p.x = f2bf(d * v.x) | (f2bf(d * v.y) << 16);
    p.y = f2bf(d * v.z) | (f2bf(d * v.w) << 16);
    ((uint2*)out)[t] = p;
}

// Pack W[K][N] f32 -> WT[N][K] bf16 (transposed). total = K*N threads.
__global__ __launch_bounds__(256)
void pack_wt(const float* __restrict__ W, unsigned short* __restrict__ WT,
             int K, int N) {
    int t = blockIdx.x * 256 + threadIdx.x;
    if (t < K * N) {
        int n = t / K, k = t - n * K;
        WT[t] = (unsigned short)f2bf(W[(size_t)k * N + n]);
    }
}

// ---------------------------------------------------------------------------
// Aggregation 1: Ab[i,:] = f2bf( dis[i] * (Xs[i,:] + sum_e Xs[src,:]) )
// ---------------------------------------------------------------------------
__global__ __launch_bounds__(256)
void agg_x_bf16(const unsigned* __restrict__ Xb, const float* __restrict__ dis,
                const int* __restrict__ rs, const int* __restrict__ srcs,
                unsigned* __restrict__ Ab) {
    int wid = threadIdx.x >> 6, lane = threadIdx.x & 63;
    int i = blockIdx.x * 4 + wid;
    if (i >= N_NODES) return;
    unsigned sv = Xb[(size_t)i * 64 + lane];
    float a0 = bflo(sv), a1 = bfhi(sv);
    int e = rs[i], e1 = rs[i + 1];
    for (; e + 3 < e1; e += 4) {
        int s0 = srcs[e], s1 = srcs[e + 1], s2 = srcs[e + 2], s3 = srcs[e + 3];
        unsigned v0 = Xb[(size_t)s0 * 64 + lane];
        unsigned v1 = Xb[(size_t)s1 * 64 + lane];
        unsigned v2 = Xb[(size_t)s2 * 64 + lane];
        unsigned v3 = Xb[(size_t)s3 * 64 + lane];
        a0 += (bflo(v0) + bflo(v1)) + (bflo(v2) + bflo(v3));
        a1 += (bfhi(v0) + bfhi(v1)) + (bfhi(v2) + bfhi(v3));
    }
    for (; e < e1; ++e) {
        unsigned v = Xb[(size_t)srcs[e] * 64 + lane];
        a0 += bflo(v); a1 += bfhi(v);
    }
    float di = dis[i];
    Ab[(size_t)i * 64 + lane] = f2bf(di * a0) | (f2bf(di * a1) << 16);
}

// ---------------------------------------------------------------------------
// Aggregation 2 fused bias+ReLU+dot(Wfc) -> pernode scalar.
// Gs rows pre-scaled by dis in gemm2 epilogue.
// ---------------------------------------------------------------------------
__global__ __launch_bounds__(256)
void agg_g_pool_bf16(const unsigned* __restrict__ Gb, const float* __restrict__ dis,
                     const int* __restrict__ rs, const int* __restrict__ srcs,
                     const float* __restrict__ b2, const float* __restrict__ wfc,
                     float* __restrict__ pernode) {
    int wid = threadIdx.x >> 6, lane = threadIdx.x & 63;
    int i = blockIdx.x * 4 + wid;
    if (i >= N_NODES) return;
    unsigned sv = Gb[(size_t)i * 64 + lane];
    float a0 = bflo(sv), a1 = bfhi(sv);
    int e = rs[i], e1 = rs[i + 1];
    for (; e + 3 < e1; e += 4) {
        int s0 = srcs[e], s1 = srcs[e + 1], s2 = srcs[e + 2], s3 = srcs[e + 3];
        unsigned v0 = Gb[(size_t)s0 * 64 + lane];
        unsigned v1 = Gb[(size_t)s1 * 64 + lane];
        unsigned v2 = Gb[(size_t)s2 * 64 + lane];
        unsigned v3 = Gb[(size_t)s3 * 64 + lane];
        a0 += (bflo(v0) + bflo(v1)) + (bflo(v2) + bflo(v3));
        a1 += (bfhi(v0) + bfhi(v1)) + (bfhi(v2) + bfhi(v3));
    }
    for (; e < e1; ++e) {
        unsigned v = Gb[(size_t)srcs[e] * 64 + lane];
        a0 += bflo(v); a1 += bfhi(v);
    }
    float di = dis[i];
    int c0 = lane * 2;
    float r = fmaxf(di * a0 + b2[c0], 0.f) * wfc[c0]
            + fmaxf(di * a1 + b2[c0 + 1], 0.f) * wfc[c0 + 1];
#pragma unroll
    for (int off = 32; off > 0; off >>= 1) r += __shfl_down(r, off, 64);
    if (lane == 0) pernode[i] = r;
}

__global__ __launch_bounds__(256)
void reduce_pernode(const float* __restrict__ pn, float* __restrict__ accbuf) {
    __shared__ float red[256];
    float s = 0.f;
    for (int i = blockIdx.x * 256 + threadIdx.x; i < N_NODES; i += gridDim.x * 256)
        s += pn[i];
    red[threadIdx.x] = s;
    __syncthreads();
    for (int off = 128; off > 0; off >>= 1) {
        if (threadIdx.x < off) red[threadIdx.x] += red[threadIdx.x + off];
        __syncthreads();
    }
    if (threadIdx.x == 0) atomicAdd(accbuf, red[0]);
}

__global__ void finalize(const float* __restrict__ accbuf,
                         const float* __restrict__ bfc, float* __restrict__ out) {
    out[0] = accbuf[0] * (1.0f / (float)N_NODES) + bfc[0];
}

// ---------------------------------------------------------------------------
// bf16 MFMA GEMM: C[M,N] = A[M,K] @ WT[N,K]^T, f32 accum, bf16 out.
// MODE 0: epilogue v = relu(v + bias[col]);  MODE 1: v = v * rowscale[row].
// BM=64, BN=128, BK=32; 256 threads = 4 waves, wave w -> 32x64 quadrant.
// ---------------------------------------------------------------------------
template<int MODE>
__global__ __launch_bounds__(256)
void gemm_mfma(const unsigned short* __restrict__ A,   // [M][K] bf16
               const unsigned short* __restrict__ WT,  // [N][K] bf16
               const float* __restrict__ bias,         // [N]   (MODE 0)
               const float* __restrict__ rowscale,     // [M]   (MODE 1)
               unsigned short* __restrict__ C,         // [M][N] bf16
               int M, int N, int K) {
    __shared__ __align__(16) unsigned short Asl[4 * 64 * 8];    // 4KB
    __shared__ __align__(16) unsigned short Bsl[4 * 128 * 8];   // 8KB

    int tid = threadIdx.x;
    int lane = tid & 63, w = tid >> 6;
    int wr = w >> 1, wc = w & 1;
    int row0 = blockIdx.x * 64;
    int col0 = blockIdx.y * 128;

    f32x4 acc[2][4];
#pragma unroll
    for (int i = 0; i < 2; ++i)
#pragma unroll
        for (int j = 0; j < 4; ++j) acc[i][j] = (f32x4){0.f, 0.f, 0.f, 0.f};

    int arow = min(row0 + (tid & 63), M - 1);      // clamp: OOB rows read valid mem
    const unsigned short* agp = A + (size_t)arow * K + (tid >> 6) * 8;
    const unsigned short* bgp0 = WT + (size_t)(col0 + (tid & 127)) * K + (tid >> 7) * 8;
    const unsigned short* bgp1 = bgp0 + 16;        // kb += 2

    const bf16x8* Av = (const bf16x8*)Asl;
    const bf16x8* Bv = (const bf16x8*)Bsl;
    int aidx = (lane >> 4) * 64 + wr * 32 + (lane & 15);    // + fm*16
    int bidx = (lane >> 4) * 128 + wc * 64 + (lane & 15);   // + fn*16

    for (int k0 = 0; k0 < K; k0 += 32) {
        *(float4*)&Asl[tid * 8]         = *(const float4*)(agp + k0);
        *(float4*)&Bsl[tid * 8]         = *(const float4*)(bgp0 + k0);
        *(float4*)&Bsl[(tid + 256) * 8] = *(const float4*)(bgp1 + k0);
        __syncthreads();

        bf16x8 af[2], bf[4];
#pragma unroll
        for (int fm = 0; fm < 2; ++fm) af[fm] = Av[aidx + fm * 16];
#pragma unroll
        for (int fn = 0; fn < 4; ++fn) bf[fn] = Bv[bidx + fn * 16];
#pragma unroll
        for (int fm = 0; fm < 2; ++fm)
#pragma unroll
            for (int fn = 0; fn < 4; ++fn)
                acc[fm][fn] = __builtin_amdgcn_mfma_f32_16x16x32_bf16(
                    af[fm], bf[fn], acc[fm][fn], 0, 0, 0);
        __syncthreads();
    }

    float bv[4];
    if (MODE == 0) {
#pragma unroll
        for (int fn = 0; fn < 4; ++fn)
            bv[fn] = bias[col0 + wc * 64 + fn * 16 + (lane & 15)];
    }
#pragma unroll
    for (int fm = 0; fm < 2; ++fm) {
#pragma unroll
        for (int r = 0; r < 4; ++r) {
            int row = row0 + wr * 32 + fm * 16 + (lane >> 4) * 4 + r;
            if (row < M) {
                float rsc = (MODE == 1) ? rowscale[row] : 0.f;
#pragma unroll
                for (int fn = 0; fn < 4; ++fn) {
                    int col = col0 + wc * 64 + fn * 16 + (lane & 15);
                    float v = acc[fm][fn][r];
                    if (MODE == 0) v = fmaxf(v + bv[fn], 0.f);
                    else           v = v * rsc;
                    C[(size_t)row * N + col] = (unsigned short)f2bf(v);
                }
            }
        }
    }
}

// ---------------------------------------------------------------------------
// launcher
// ---------------------------------------------------------------------------
extern "C" void kernel_launch(void* const* d_in, const int* in_sizes, int n_in,
                              void* d_out, int out_size, void* d_ws, size_t ws_size,
                              hipStream_t stream) {
    const float* x   = (const float*)d_in[0];
    const int*   ei  = (const int*)d_in[1];     // int32 per harness contract
    const float* W1  = (const float*)d_in[2];
    const float* b1  = (const float*)d_in[3];
    const float* W2  = (const float*)d_in[4];
    const float* b2  = (const float*)d_in[5];
    const float* Wfc = (const float*)d_in[6];
    const float* bfc = (const float*)d_in[7];
    float* out = (float*)d_out;

    char* ws = (char*)d_ws;
    size_t off = 0;
    auto carve = [&](size_t bytes) {
        void* p = ws + off;
        off += (bytes + 255) & ~(size_t)255;
        return p;
    };
    int*   cnt      = (int*)  carve((size_t)N_NODES * 4);
    int*   rs_tmp   = (int*)  carve((size_t)N_NODES * 4);
    int*   rs       = (int*)  carve((size_t)(N_NODES + 1) * 4);
    int*   partials = (int*)  carve((size_t)NSCAN * 4);
    int*   offs     = (int*)  carve((size_t)NSCAN * 4);
    float* dis      = (float*)carve((size_t)N_NODES * 4);
    int*   ord      = (int*)  carve((size_t)N_EDGES * 4);
    int*   srcs     = (int*)  carve((size_t)N_EDGES * 4);
    unsigned* Xb    = (unsigned*)carve((size_t)N_NODES * 64 * 4);        // dis-scaled x bf16
    unsigned* Ab    = (unsigned*)carve((size_t)N_NODES * 64 * 4);        // agg1 out bf16
    unsigned short* h1b = (unsigned short*)carve((size_t)N_NODES * HID * 2);
    unsigned short* Gb  = (unsigned short*)carve((size_t)N_NODES * HID2 * 2);
    unsigned short* WT1 = (unsigned short*)carve((size_t)HID * IN_DIM * 2);
    unsigned short* WT2 = (unsigned short*)carve((size_t)HID2 * HID * 2);
    float* pernode  = (float*)carve((size_t)N_NODES * 4);
    float* accbuf   = (float*)carve(4);

    hipMemsetAsync(cnt,    0, (size_t)N_NODES * 4, stream);
    hipMemsetAsync(accbuf, 0, 4, stream);

    const int TB = 256;
    const int EB = (N_EDGES + TB - 1) / TB;

    count_ord<<<EB, TB, 0, stream>>>(ei, cnt, ord);
    scanA<<<NSCAN, TB, 0, stream>>>(cnt, rs_tmp, partials, dis);
    scanB<<<1, TB, 0, stream>>>(partials, offs);
    scanC<<<NSCAN, TB, 0, stream>>>(rs_tmp, offs, rs);
    fill_csr<<<EB, TB, 0, stream>>>(ei, rs, ord, srcs);

    pack_x_scaled<<<(N_NODES * IN_DIM / 4) / 256, TB, 0, stream>>>(x, dis, Xb);
    pack_wt<<<(IN_DIM * HID + 255) / 256, TB, 0, stream>>>(W1, WT1, IN_DIM, HID);
    pack_wt<<<(HID * HID2 + 255) / 256, TB, 0, stream>>>(W2, WT2, HID, HID2);

    // layer 1: aggregate (bf16) -> Ab; MFMA GEMM +b1+relu -> h1b
    agg_x_bf16<<<(N_NODES + 3) / 4, TB, 0, stream>>>(Xb, dis, rs, srcs, Ab);
    {
        dim3 grid((N_NODES + 63) / 64, HID / 128);
        gemm_mfma<0><<<grid, TB, 0, stream>>>((const unsigned short*)Ab, WT1, b1,
                                              nullptr, h1b, N_NODES, HID, IN_DIM);
    }
    // layer 2: MFMA GEMM h1 @ W2, epilogue scales rows by dis -> Gb
    {
        dim3 grid((N_NODES + 63) / 64, HID2 / 128);
        gemm_mfma<1><<<grid, TB, 0, stream>>>(h1b, WT2, nullptr, dis,
                                              Gb, N_NODES, HID2, HID);
    }
    agg_g_pool_bf16<<<(N_NODES + 3) / 4, TB, 0, stream>>>((const unsigned*)Gb, dis,
                                                          rs, srcs, b2, Wfc, pernode);
    reduce_pernode<<<32, TB, 0, stream>>>(pernode, accbuf);
    finalize<<<1, 1, 0, stream>>>(accbuf, bfc, out);
}